// Round 1
// baseline (5638.340 us; speedup 1.0000x reference)
//
#include <hip/hip_runtime.h>
#include <math.h>

// GenreAdaptiveLayer — fp32 correctness-first baseline.
//
// Decomposition:
//   attention path: ae'[g,h] = emb·Wa1[D:] + ba1      (tiny GEMM, fused bias)
//                   ah = x·Wa1[:D]                     (GEMM, MODE 0)
//                   scores/softmax -> w[b,g]           (1 wave per row)
//   main path, per g (h-buffer reused, serial on stream):
//     GEMM1: h = x·W1[g] + b1[g], fused per-row sum/sumsq via
//            16-lane shuffle reduce + global atomics     (MODE 1)
//     LN:    a' = w[b,g] * leaky((h-mu)*rstd*ln_g + ln_b)  in-place
//     GEMM2: out (+)= a'·W2[g] + w[b,g]*b2[g]            (MODE 2)
//
// ws layout (floats): ah[B*H] | hbuf[B*H] | aep[G*H] | w[B*G] | ssum[B] | ssq[B]
//   total ~64.3 MB.

#define B_SZ 4096
#define D_SZ 1024
#define H_SZ 2048
#define G_SZ 10
#define EPS_F 1e-5f
#define SLOPE_F 0.2f

#define BM 128
#define BN 128
#define BK 16
#define TM 8
#define TN 8

// ---------------------------------------------------------------- GEMM
// C[M,N] (+)= A[M,K](row-major, lda) * B[K,N](row-major, ldb)
// MODE 0: plain store
// MODE 1: +bias[col], store, and atomicAdd per-row sum/sumsq to ssum/ssq
// MODE 2: +rowscale[row]*bias[col]; ACCUM ? C += : C =
template<int MODE, bool ACCUM>
__global__ __launch_bounds__(256) void gemm_f32(
    const float* __restrict__ A, int lda,
    const float* __restrict__ B, int ldb,
    float* __restrict__ C, int ldc,
    int M, int N, int K,
    const float* __restrict__ bias,
    const float* __restrict__ rowscale, int rs_stride,
    float* __restrict__ ssum, float* __restrict__ ssq)
{
    __shared__ float As[BK][BM + 4];
    __shared__ float Bs[BK][BN + 4];

    const int tid = threadIdx.x;
    const int tx = tid & 15;   // col group (lane % 16)
    const int ty = tid >> 4;   // row group
    const int bm0 = blockIdx.y * BM;
    const int bn0 = blockIdx.x * BN;

    float acc[TM][TN];
#pragma unroll
    for (int i = 0; i < TM; i++)
#pragma unroll
        for (int j = 0; j < TN; j++) acc[i][j] = 0.f;

    // global staging indices
    const int arow = tid >> 2;          // 0..63
    const int acol = (tid & 3) * 4;     // 0,4,8,12
    const int brow = tid >> 5;          // 0..7
    const int bcol = (tid & 31) * 4;    // 0..124

    for (int k0 = 0; k0 < K; k0 += BK) {
        float4 a0 = *reinterpret_cast<const float4*>(&A[(size_t)(bm0 + arow) * lda + k0 + acol]);
        float4 a1 = *reinterpret_cast<const float4*>(&A[(size_t)(bm0 + arow + 64) * lda + k0 + acol]);
        float4 b0 = *reinterpret_cast<const float4*>(&B[(size_t)(k0 + brow) * ldb + bn0 + bcol]);
        float4 b1 = *reinterpret_cast<const float4*>(&B[(size_t)(k0 + brow + 8) * ldb + bn0 + bcol]);

        __syncthreads();  // protect previous iteration's LDS reads

        As[acol + 0][arow] = a0.x;  As[acol + 1][arow] = a0.y;
        As[acol + 2][arow] = a0.z;  As[acol + 3][arow] = a0.w;
        As[acol + 0][arow + 64] = a1.x;  As[acol + 1][arow + 64] = a1.y;
        As[acol + 2][arow + 64] = a1.z;  As[acol + 3][arow + 64] = a1.w;
        *reinterpret_cast<float4*>(&Bs[brow][bcol]) = b0;
        *reinterpret_cast<float4*>(&Bs[brow + 8][bcol]) = b1;

        __syncthreads();

#pragma unroll
        for (int k = 0; k < BK; k++) {
            float4 A0 = *reinterpret_cast<const float4*>(&As[k][ty * TM]);
            float4 A1 = *reinterpret_cast<const float4*>(&As[k][ty * TM + 4]);
            float4 B0 = *reinterpret_cast<const float4*>(&Bs[k][tx * TN]);
            float4 B1 = *reinterpret_cast<const float4*>(&Bs[k][tx * TN + 4]);
            float ar[TM] = {A0.x, A0.y, A0.z, A0.w, A1.x, A1.y, A1.z, A1.w};
            float br[TN] = {B0.x, B0.y, B0.z, B0.w, B1.x, B1.y, B1.z, B1.w};
#pragma unroll
            for (int i = 0; i < TM; i++)
#pragma unroll
                for (int j = 0; j < TN; j++)
                    acc[i][j] = fmaf(ar[i], br[j], acc[i][j]);
        }
    }

    const int row0 = bm0 + ty * TM;
    const int col0 = bn0 + tx * TN;

    if (MODE == 0) {
#pragma unroll
        for (int i = 0; i < TM; i++) {
            float4* cp = reinterpret_cast<float4*>(&C[(size_t)(row0 + i) * ldc + col0]);
            cp[0] = make_float4(acc[i][0], acc[i][1], acc[i][2], acc[i][3]);
            cp[1] = make_float4(acc[i][4], acc[i][5], acc[i][6], acc[i][7]);
        }
    } else if (MODE == 1) {
        float bsv[TN];
#pragma unroll
        for (int j = 0; j < TN; j++) bsv[j] = bias[col0 + j];
#pragma unroll
        for (int i = 0; i < TM; i++) {
            float s = 0.f, q = 0.f;
#pragma unroll
            for (int j = 0; j < TN; j++) {
                float v = acc[i][j] + bsv[j];
                acc[i][j] = v;
                s += v;
                q += v * v;
            }
            // reduce across the 16 col-group lanes (tx = lane % 16)
#pragma unroll
            for (int m = 1; m < 16; m <<= 1) {
                s += __shfl_xor(s, m, 64);
                q += __shfl_xor(q, m, 64);
            }
            if (tx == 0) {
                atomicAdd(&ssum[row0 + i], s);
                atomicAdd(&ssq[row0 + i], q);
            }
            float4* cp = reinterpret_cast<float4*>(&C[(size_t)(row0 + i) * ldc + col0]);
            cp[0] = make_float4(acc[i][0], acc[i][1], acc[i][2], acc[i][3]);
            cp[1] = make_float4(acc[i][4], acc[i][5], acc[i][6], acc[i][7]);
        }
    } else {  // MODE 2
        float bsv[TN];
#pragma unroll
        for (int j = 0; j < TN; j++) bsv[j] = bias[col0 + j];
#pragma unroll
        for (int i = 0; i < TM; i++) {
            float rs = rowscale[(size_t)(row0 + i) * rs_stride];
            float v[TN];
#pragma unroll
            for (int j = 0; j < TN; j++) v[j] = acc[i][j] + rs * bsv[j];
            float4* cp = reinterpret_cast<float4*>(&C[(size_t)(row0 + i) * ldc + col0]);
            if (ACCUM) {
                float4 c0 = cp[0], c1 = cp[1];
                cp[0] = make_float4(c0.x + v[0], c0.y + v[1], c0.z + v[2], c0.w + v[3]);
                cp[1] = make_float4(c1.x + v[4], c1.y + v[5], c1.z + v[6], c1.w + v[7]);
            } else {
                cp[0] = make_float4(v[0], v[1], v[2], v[3]);
                cp[1] = make_float4(v[4], v[5], v[6], v[7]);
            }
        }
    }
}

// ------------------------------------------------- ae'[g,h] = emb·Wa1[D:] + ba1
__global__ __launch_bounds__(256) void ae_kernel(
    const float* __restrict__ emb, const float* __restrict__ Wa1,
    const float* __restrict__ ba1, float* __restrict__ aep)
{
    const int h = blockIdx.x * 256 + threadIdx.x;
    float acc[G_SZ];
#pragma unroll
    for (int g = 0; g < G_SZ; g++) acc[g] = 0.f;
#pragma unroll 4
    for (int k = 0; k < H_SZ; k++) {
        float wv = Wa1[(size_t)(D_SZ + k) * H_SZ + h];
#pragma unroll
        for (int g = 0; g < G_SZ; g++)
            acc[g] = fmaf(emb[g * H_SZ + k], wv, acc[g]);  // uniform addr -> s_load
    }
    float bb = ba1[h];
#pragma unroll
    for (int g = 0; g < G_SZ; g++) aep[(size_t)g * H_SZ + h] = acc[g] + bb;
}

// ----------------------------------- scores + softmax -> w[b,g]; 1 wave per b
__global__ __launch_bounds__(64) void scores_softmax(
    const float* __restrict__ ah, const float* __restrict__ aep,
    const float* __restrict__ Wa2, const float* __restrict__ ba2,
    float* __restrict__ w)
{
    const int b = blockIdx.x;
    const int lane = threadIdx.x;
    float accg[G_SZ];
#pragma unroll
    for (int g = 0; g < G_SZ; g++) accg[g] = 0.f;

    for (int j = 0; j < H_SZ / 64; j++) {
        const int h = j * 64 + lane;
        const float av = ah[(size_t)b * H_SZ + h];
        const float wv = Wa2[h];
#pragma unroll
        for (int g = 0; g < G_SZ; g++) {
            float v = av + aep[(size_t)g * H_SZ + h];
            v = v > 0.f ? v : SLOPE_F * v;
            accg[g] = fmaf(v, wv, accg[g]);
        }
    }
#pragma unroll
    for (int g = 0; g < G_SZ; g++)
#pragma unroll
        for (int m = 1; m < 64; m <<= 1) accg[g] += __shfl_xor(accg[g], m, 64);

    if (lane == 0) {
        const float bb = ba2[0];
        float mx = -1e30f;
#pragma unroll
        for (int g = 0; g < G_SZ; g++) {
            accg[g] += bb;
            mx = fmaxf(mx, accg[g]);
        }
        float sum = 0.f;
#pragma unroll
        for (int g = 0; g < G_SZ; g++) {
            accg[g] = expf(accg[g] - mx);
            sum += accg[g];
        }
        const float inv = 1.f / sum;
#pragma unroll
        for (int g = 0; g < G_SZ; g++) w[(size_t)b * G_SZ + g] = accg[g] * inv;
    }
}

// -------------------- in-place: a' = w[b,g] * leaky(LN(h)*ln_g + ln_b)
__global__ __launch_bounds__(256) void ln_leaky_scale(
    float* __restrict__ hbuf,
    const float* __restrict__ ssum, const float* __restrict__ ssq,
    const float* __restrict__ ln_g, const float* __restrict__ ln_b,
    const float* __restrict__ w, int g)
{
    const int idx4 = blockIdx.x * 256 + threadIdx.x;  // one float4 each
    const int b = idx4 / (H_SZ / 4);
    const int h4 = (idx4 % (H_SZ / 4)) * 4;

    const float mu = ssum[b] * (1.f / H_SZ);
    const float var = ssq[b] * (1.f / H_SZ) - mu * mu;
    const float rstd = rsqrtf(var + EPS_F);
    const float wv = w[(size_t)b * G_SZ + g];

    float4 hv = *reinterpret_cast<const float4*>(&hbuf[(size_t)b * H_SZ + h4]);
    float4 gv = *reinterpret_cast<const float4*>(&ln_g[h4]);
    float4 bv = *reinterpret_cast<const float4*>(&ln_b[h4]);

    float r[4] = {hv.x, hv.y, hv.z, hv.w};
    float gg[4] = {gv.x, gv.y, gv.z, gv.w};
    float bb[4] = {bv.x, bv.y, bv.z, bv.w};
#pragma unroll
    for (int c = 0; c < 4; c++) {
        float t = (r[c] - mu) * rstd * gg[c] + bb[c];
        t = t > 0.f ? t : SLOPE_F * t;
        r[c] = wv * t;
    }
    *reinterpret_cast<float4*>(&hbuf[(size_t)b * H_SZ + h4]) =
        make_float4(r[0], r[1], r[2], r[3]);
}

// ---------------------------------------------------------------- launch
extern "C" void kernel_launch(void* const* d_in, const int* in_sizes, int n_in,
                              void* d_out, int out_size, void* d_ws, size_t ws_size,
                              hipStream_t stream)
{
    const float* x    = (const float*)d_in[0];
    const float* emb  = (const float*)d_in[1];
    const float* W1   = (const float*)d_in[2];
    const float* b1   = (const float*)d_in[3];
    const float* ln_g = (const float*)d_in[4];
    const float* ln_b = (const float*)d_in[5];
    const float* W2   = (const float*)d_in[6];
    const float* b2   = (const float*)d_in[7];
    const float* Wa1  = (const float*)d_in[8];
    const float* ba1  = (const float*)d_in[9];
    const float* Wa2  = (const float*)d_in[10];
    const float* ba2  = (const float*)d_in[11];
    float* out = (float*)d_out;

    float* ws   = (float*)d_ws;
    float* ah   = ws;                               // B*H
    float* hbuf = ah + (size_t)B_SZ * H_SZ;         // B*H
    float* aep  = hbuf + (size_t)B_SZ * H_SZ;       // G*H
    float* wbuf = aep + (size_t)G_SZ * H_SZ;        // B*G
    float* ssum = wbuf + (size_t)B_SZ * G_SZ;       // B
    float* ssq  = ssum + B_SZ;                      // B

    // ---- attention path
    ae_kernel<<<H_SZ / 256, 256, 0, stream>>>(emb, Wa1, ba1, aep);

    gemm_f32<0, false><<<dim3(H_SZ / BN, B_SZ / BM), 256, 0, stream>>>(
        x, D_SZ, Wa1, H_SZ, ah, H_SZ, B_SZ, H_SZ, D_SZ,
        nullptr, nullptr, 0, nullptr, nullptr);

    scores_softmax<<<B_SZ, 64, 0, stream>>>(ah, aep, Wa2, ba2, wbuf);

    // ---- main path, per genre
    for (int g = 0; g < G_SZ; g++) {
        hipMemsetAsync(ssum, 0, 2 * B_SZ * sizeof(float), stream);

        gemm_f32<1, false><<<dim3(H_SZ / BN, B_SZ / BM), 256, 0, stream>>>(
            x, D_SZ, W1 + (size_t)g * D_SZ * H_SZ, H_SZ, hbuf, H_SZ,
            B_SZ, H_SZ, D_SZ, b1 + (size_t)g * H_SZ,
            nullptr, 0, ssum, ssq);

        ln_leaky_scale<<<(B_SZ * H_SZ / 4) / 256, 256, 0, stream>>>(
            hbuf, ssum, ssq, ln_g + (size_t)g * H_SZ, ln_b + (size_t)g * H_SZ,
            wbuf, g);

        if (g == 0) {
            gemm_f32<2, false><<<dim3(D_SZ / BN, B_SZ / BM), 256, 0, stream>>>(
                hbuf, H_SZ, W2 + (size_t)g * H_SZ * D_SZ, D_SZ, out, D_SZ,
                B_SZ, D_SZ, H_SZ, b2 + (size_t)g * D_SZ,
                wbuf + g, G_SZ, nullptr, nullptr);
        } else {
            gemm_f32<2, true><<<dim3(D_SZ / BN, B_SZ / BM), 256, 0, stream>>>(
                hbuf, H_SZ, W2 + (size_t)g * H_SZ * D_SZ, D_SZ, out, D_SZ,
                B_SZ, D_SZ, H_SZ, b2 + (size_t)g * D_SZ,
                wbuf + g, G_SZ, nullptr, nullptr);
        }
    }
    (void)in_sizes; (void)n_in; (void)out_size; (void)ws_size;
}

// Round 4
// 2883.478 us; speedup vs baseline: 1.9554x; 1.9554x over previous
//
#include <hip/hip_runtime.h>
#include <math.h>

// GenreAdaptiveLayer — split-bf16 MFMA rewrite.
//
//   x_split  = [hi|lo] bf16 of x                 (B, 2D)
//   Wt       = [hi|lo] bf16 of W^T (per use)     (N, 2K), reused buffer
//   GEMM(A_split, Bt_split) over K' = 3K: terms hi*hi + lo*hi + hi*lo
//   attention: ah = x·Wax (MFMA) ; ae via fp32 atomics ; scores/softmax
//   per g: Wt<-W1g^T ; h = x·W1g (MFMA) ; LN+leaky+w-scale -> a'_split ;
//          Wt<-W2g^T ; out (+)= a'·W2g + w*b2 (MFMA epilogue)
//
// ws: x_split 16.8MB | Wt 8.4MB | asplit 33.6MB | hah 33.6MB | aep | wbuf
//     total ~92.5 MB

#define B_SZ 4096
#define D_SZ 1024
#define H_SZ 2048
#define G_SZ 10
#define EPS_F 1e-5f
#define SLOPE_F 0.2f

typedef __attribute__((ext_vector_type(8))) short short8;
typedef __attribute__((ext_vector_type(4))) float f32x4;

__device__ __forceinline__ unsigned short f2bf_rne(float f) {
    unsigned u = __float_as_uint(f);
    unsigned r = u + 0x7fffu + ((u >> 16) & 1u);
    return (unsigned short)(r >> 16);
}

// ---------------------------------------------------------- x -> [hi|lo]
__global__ __launch_bounds__(256) void convert_x_split(
    const float* __restrict__ x, short* __restrict__ xs)
{
    const int idx = (blockIdx.x * 256 + threadIdx.x) * 8;
    const int b = idx >> 10;          // / D_SZ
    const int d = idx & (D_SZ - 1);
    float4 v0 = *reinterpret_cast<const float4*>(&x[idx]);
    float4 v1 = *reinterpret_cast<const float4*>(&x[idx + 4]);
    float v[8] = {v0.x, v0.y, v0.z, v0.w, v1.x, v1.y, v1.z, v1.w};
    short8 hi8, lo8;
#pragma unroll
    for (int e = 0; e < 8; e++) {
        unsigned short hb = f2bf_rne(v[e]);
        float hf = __uint_as_float(((unsigned)hb) << 16);
        hi8[e] = (short)hb;
        lo8[e] = (short)f2bf_rne(v[e] - hf);
    }
    *reinterpret_cast<short8*>(&xs[(size_t)b * (2 * D_SZ) + d]) = hi8;
    *reinterpret_cast<short8*>(&xs[(size_t)b * (2 * D_SZ) + D_SZ + d]) = lo8;
}

// ------------------------------- W (K,N) fp32 -> Wt (N, 2K) bf16 [hi|lo]
__global__ __launch_bounds__(256) void transpose_split(
    const float* __restrict__ W, short* __restrict__ out, int K, int N)
{
    __shared__ float tile[32][33];
    const int k0 = blockIdx.x * 32, n0 = blockIdx.y * 32;
    const int tj = threadIdx.x & 31, ti = threadIdx.x >> 5;  // ti 0..7
#pragma unroll
    for (int p = 0; p < 4; p++) {
        int i = ti + p * 8;
        tile[i][tj] = W[(size_t)(k0 + i) * N + n0 + tj];
    }
    __syncthreads();
#pragma unroll
    for (int p = 0; p < 4; p++) {
        int i = ti + p * 8;
        float v = tile[tj][i];             // = W[k0+tj][n0+i]
        int orow = n0 + i, ocol = k0 + tj;
        unsigned short hb = f2bf_rne(v);
        float hf = __uint_as_float(((unsigned)hb) << 16);
        unsigned short lb = f2bf_rne(v - hf);
        out[(size_t)orow * (2 * K) + ocol] = (short)hb;
        out[(size_t)orow * (2 * K) + K + ocol] = (short)lb;
    }
}

// ---------------------------------------------------------------- GEMM
// A (M, 2K) bf16 [hi|lo]; Bt (N, 2K) bf16 [hi|lo]; C (M,N) fp32.
// SPLIT: K' = 3K with region remap (hi*hi + lo*hi + hi*lo).
// MODE 0: C = acc.  MODE 2: C (+)= acc + rowscale[row]*bias[col].
template<bool SPLIT, int MODE, bool ACCUM>
__global__ __launch_bounds__(256) void gemm_mfma(
    const short* __restrict__ A, const short* __restrict__ Bt,
    float* __restrict__ C, int ldc, int M, int N, int K,
    const float* __restrict__ bias,
    const float* __restrict__ rowscale, int rs_stride)
{
    __shared__ short As[128 * 32];
    __shared__ short Bs[128 * 32];
    const int tid = threadIdx.x;
    const int lane = tid & 63;
    const int w = tid >> 6;
    const int wm = w >> 1, wn = w & 1;
    const int bm0 = blockIdx.y * 128, bn0 = blockIdx.x * 128;
    const int lda = SPLIT ? 2 * K : K;

    f32x4 acc[4][4];
#pragma unroll
    for (int i = 0; i < 4; i++)
#pragma unroll
        for (int j = 0; j < 4; j++) acc[i][j] = (f32x4)0.f;

    const int ksteps = (SPLIT ? 3 * K : K) / 32;
    for (int t = 0; t < ksteps; t++) {
        const int kp = t * 32;
        const int aoff = SPLIT ? (kp < 2 * K ? kp : kp - 2 * K) : kp;
        const int boff = SPLIT ? (kp < K ? kp : kp - K) : kp;

        __syncthreads();  // previous iteration's frag reads complete
#pragma unroll
        for (int p = 0; p < 2; p++) {
            const int q = tid + p * 256;
            const int r = q >> 2, s = q & 3;
            const int lc = s ^ ((r >> 1) & 3);  // pre-swizzled source chunk
            const short* ga = A + (size_t)(bm0 + r) * lda + aoff + lc * 8;
            const short* gb = Bt + (size_t)(bn0 + r) * lda + boff + lc * 8;
            __builtin_amdgcn_global_load_lds(
                (const __attribute__((address_space(1))) void*)ga,
                (__attribute__((address_space(3))) void*)(As + q * 8), 16, 0, 0);
            __builtin_amdgcn_global_load_lds(
                (const __attribute__((address_space(1))) void*)gb,
                (__attribute__((address_space(3))) void*)(Bs + q * 8), 16, 0, 0);
        }
        __syncthreads();  // drains vmcnt before barrier (compiler-enforced)

        const int fr = lane & 15, kc = lane >> 4;
        short8 af[4], bfr[4];
#pragma unroll
        for (int i = 0; i < 4; i++) {
            const int ar = wm * 64 + i * 16 + fr;
            af[i] = *reinterpret_cast<const short8*>(
                (const char*)As + ar * 64 + ((kc ^ ((ar >> 1) & 3)) << 4));
            const int br = wn * 64 + i * 16 + fr;
            bfr[i] = *reinterpret_cast<const short8*>(
                (const char*)Bs + br * 64 + ((kc ^ ((br >> 1) & 3)) << 4));
        }
#pragma unroll
        for (int i = 0; i < 4; i++)
#pragma unroll
            for (int j = 0; j < 4; j++)
                acc[i][j] = __builtin_amdgcn_mfma_f32_16x16x32_bf16(
                    af[i], bfr[j], acc[i][j], 0, 0, 0);
    }

    // epilogue: C/D layout col = lane&15, row = (lane>>4)*4 + reg
    const int fr = lane & 15, fq = lane >> 4;
#pragma unroll
    for (int i = 0; i < 4; i++) {
#pragma unroll
        for (int j = 0; j < 4; j++) {
            const int col = bn0 + wn * 64 + j * 16 + fr;
            const int row0 = bm0 + wm * 64 + i * 16 + fq * 4;
#pragma unroll
            for (int r = 0; r < 4; r++) {
                const int row = row0 + r;
                float v = acc[i][j][r];
                if (MODE == 2) {
                    v += rowscale[(size_t)row * rs_stride] * bias[col];
                    if (ACCUM) v += C[(size_t)row * ldc + col];
                }
                C[(size_t)row * ldc + col] = v;
            }
        }
    }
}

// --------------------------------------------- aep[g,h] = ba1[h] (init)
__global__ __launch_bounds__(256) void aep_init(
    const float* __restrict__ ba1, float* __restrict__ aep)
{
    const int i = blockIdx.x * 256 + threadIdx.x;
    aep[i] = ba1[i & (H_SZ - 1)];
}

// -------------------------- aep[g,h] += sum_k emb[g,k]*Wa1[D+k][h] (partial)
__global__ __launch_bounds__(256) void ae_partial(
    const float* __restrict__ emb, const float* __restrict__ Wa1,
    float* __restrict__ aep)
{
    const int h = blockIdx.x * 256 + threadIdx.x;
    const int k0 = blockIdx.y * 256;
    float acc[G_SZ];
#pragma unroll
    for (int g = 0; g < G_SZ; g++) acc[g] = 0.f;
    for (int k = k0; k < k0 + 256; k++) {
        float wv = Wa1[(size_t)(D_SZ + k) * H_SZ + h];
#pragma unroll
        for (int g = 0; g < G_SZ; g++)
            acc[g] = fmaf(emb[g * H_SZ + k], wv, acc[g]);
    }
#pragma unroll
    for (int g = 0; g < G_SZ; g++) atomicAdd(&aep[(size_t)g * H_SZ + h], acc[g]);
}

// ----------------------------------- scores + softmax -> w[b,g]; 1 wave/row
__global__ __launch_bounds__(64) void scores_softmax(
    const float* __restrict__ ah, const float* __restrict__ aep,
    const float* __restrict__ Wa2, const float* __restrict__ ba2,
    float* __restrict__ w)
{
    const int b = blockIdx.x;
    const int lane = threadIdx.x;
    float accg[G_SZ];
#pragma unroll
    for (int g = 0; g < G_SZ; g++) accg[g] = 0.f;

    for (int j = 0; j < H_SZ / 64; j++) {
        const int h = j * 64 + lane;
        const float av = ah[(size_t)b * H_SZ + h];
        const float wv = Wa2[h];
#pragma unroll
        for (int g = 0; g < G_SZ; g++) {
            float v = av + aep[(size_t)g * H_SZ + h];
            v = v > 0.f ? v : SLOPE_F * v;
            accg[g] = fmaf(v, wv, accg[g]);
        }
    }
#pragma unroll
    for (int g = 0; g < G_SZ; g++)
#pragma unroll
        for (int m = 1; m < 64; m <<= 1) accg[g] += __shfl_xor(accg[g], m, 64);

    if (lane == 0) {
        const float bb = ba2[0];
        float mx = -1e30f;
#pragma unroll
        for (int g = 0; g < G_SZ; g++) {
            accg[g] += bb;
            mx = fmaxf(mx, accg[g]);
        }
        float sum = 0.f;
#pragma unroll
        for (int g = 0; g < G_SZ; g++) {
            accg[g] = expf(accg[g] - mx);
            sum += accg[g];
        }
        const float inv = 1.f / sum;
#pragma unroll
        for (int g = 0; g < G_SZ; g++) w[(size_t)b * G_SZ + g] = accg[g] * inv;
    }
}

// ---- one block per row: h+b1 -> stats -> w*leaky(LN) -> a'_split bf16 hi/lo
__global__ __launch_bounds__(256) void ln_split(
    const float* __restrict__ hbuf, const float* __restrict__ b1g,
    const float* __restrict__ ln_gg, const float* __restrict__ ln_bg,
    const float* __restrict__ wbuf, int g, short* __restrict__ asplit)
{
    const int b = blockIdx.x;
    const int tid = threadIdx.x;
    const int h0 = tid * 8;
    const int lane = tid & 63, wv_ = tid >> 6;
    __shared__ float red[8];

    float4 h0v = *reinterpret_cast<const float4*>(&hbuf[(size_t)b * H_SZ + h0]);
    float4 h1v = *reinterpret_cast<const float4*>(&hbuf[(size_t)b * H_SZ + h0 + 4]);
    float4 b0v = *reinterpret_cast<const float4*>(&b1g[h0]);
    float4 b1v = *reinterpret_cast<const float4*>(&b1g[h0 + 4]);
    float v[8] = {h0v.x + b0v.x, h0v.y + b0v.y, h0v.z + b0v.z, h0v.w + b0v.w,
                  h1v.x + b1v.x, h1v.y + b1v.y, h1v.z + b1v.z, h1v.w + b1v.w};

    float s = 0.f, q = 0.f;
#pragma unroll
    for (int e = 0; e < 8; e++) { s += v[e]; q += v[e] * v[e]; }
#pragma unroll
    for (int m = 1; m < 64; m <<= 1) {
        s += __shfl_xor(s, m, 64);
        q += __shfl_xor(q, m, 64);
    }
    if (lane == 0) { red[wv_ * 2] = s; red[wv_ * 2 + 1] = q; }
    __syncthreads();
    float ts = red[0] + red[2] + red[4] + red[6];
    float tq = red[1] + red[3] + red[5] + red[7];
    const float mu = ts * (1.f / H_SZ);
    const float var = tq * (1.f / H_SZ) - mu * mu;
    const float rstd = rsqrtf(var + EPS_F);
    const float ww = wbuf[(size_t)b * G_SZ + g];

    float4 g0v = *reinterpret_cast<const float4*>(&ln_gg[h0]);
    float4 g1v = *reinterpret_cast<const float4*>(&ln_gg[h0 + 4]);
    float4 e0v = *reinterpret_cast<const float4*>(&ln_bg[h0]);
    float4 e1v = *reinterpret_cast<const float4*>(&ln_bg[h0 + 4]);
    float gg[8] = {g0v.x, g0v.y, g0v.z, g0v.w, g1v.x, g1v.y, g1v.z, g1v.w};
    float bb[8] = {e0v.x, e0v.y, e0v.z, e0v.w, e1v.x, e1v.y, e1v.z, e1v.w};

    short8 hi8, lo8;
#pragma unroll
    for (int e = 0; e < 8; e++) {
        float t = (v[e] - mu) * rstd * gg[e] + bb[e];
        t = t > 0.f ? t : SLOPE_F * t;
        float a = ww * t;
        unsigned short hb = f2bf_rne(a);
        float hf = __uint_as_float(((unsigned)hb) << 16);
        hi8[e] = (short)hb;
        lo8[e] = (short)f2bf_rne(a - hf);
    }
    *reinterpret_cast<short8*>(&asplit[(size_t)b * (2 * H_SZ) + h0]) = hi8;
    *reinterpret_cast<short8*>(&asplit[(size_t)b * (2 * H_SZ) + H_SZ + h0]) = lo8;
}

// ---------------------------------------------------------------- launch
extern "C" void kernel_launch(void* const* d_in, const int* in_sizes, int n_in,
                              void* d_out, int out_size, void* d_ws, size_t ws_size,
                              hipStream_t stream)
{
    const float* x    = (const float*)d_in[0];
    const float* emb  = (const float*)d_in[1];
    const float* W1   = (const float*)d_in[2];
    const float* b1   = (const float*)d_in[3];
    const float* ln_g = (const float*)d_in[4];
    const float* ln_b = (const float*)d_in[5];
    const float* W2   = (const float*)d_in[6];
    const float* b2   = (const float*)d_in[7];
    const float* Wa1  = (const float*)d_in[8];
    const float* ba1  = (const float*)d_in[9];
    const float* Wa2  = (const float*)d_in[10];
    const float* ba2  = (const float*)d_in[11];
    float* out = (float*)d_out;

    char* w8 = (char*)d_ws;
    short* x_split = (short*)w8;                               // 16,777,216 B
    short* Wt      = (short*)(w8 + 16777216);                  //  8,388,608 B
    short* asplit  = (short*)(w8 + 16777216 + 8388608);        // 33,554,432 B
    float* hah     = (float*)(w8 + 58720256);                  // 33,554,432 B
    float* aep     = (float*)(w8 + 92274688);                  //     81,920 B
    float* wbuf    = (float*)(w8 + 92356608);                  //    163,840 B

    // x -> split bf16
    convert_x_split<<<(B_SZ * D_SZ / 8) / 256, 256, 0, stream>>>(x, x_split);

    // attention path
    transpose_split<<<dim3(D_SZ / 32, H_SZ / 32), 256, 0, stream>>>(Wa1, Wt, D_SZ, H_SZ);
    aep_init<<<G_SZ * H_SZ / 256, 256, 0, stream>>>(ba1, aep);
    ae_partial<<<dim3(H_SZ / 256, 8), 256, 0, stream>>>(emb, Wa1, aep);
    gemm_mfma<true, 0, false><<<dim3(H_SZ / 128, B_SZ / 128), 256, 0, stream>>>(
        x_split, Wt, hah, H_SZ, B_SZ, H_SZ, D_SZ, nullptr, nullptr, 0);
    scores_softmax<<<B_SZ, 64, 0, stream>>>(hah, aep, Wa2, ba2, wbuf);

    // main path per genre
    for (int g = 0; g < G_SZ; g++) {
        transpose_split<<<dim3(D_SZ / 32, H_SZ / 32), 256, 0, stream>>>(
            W1 + (size_t)g * D_SZ * H_SZ, Wt, D_SZ, H_SZ);
        gemm_mfma<true, 0, false><<<dim3(H_SZ / 128, B_SZ / 128), 256, 0, stream>>>(
            x_split, Wt, hah, H_SZ, B_SZ, H_SZ, D_SZ, nullptr, nullptr, 0);
        ln_split<<<B_SZ, 256, 0, stream>>>(
            hah, b1 + (size_t)g * H_SZ, ln_g + (size_t)g * H_SZ,
            ln_b + (size_t)g * H_SZ, wbuf, g, asplit);
        transpose_split<<<dim3(H_SZ / 32, D_SZ / 32), 256, 0, stream>>>(
            W2 + (size_t)g * H_SZ * D_SZ, Wt, H_SZ, D_SZ);
        if (g == 0) {
            gemm_mfma<true, 2, false><<<dim3(D_SZ / 128, B_SZ / 128), 256, 0, stream>>>(
                asplit, Wt, out, D_SZ, B_SZ, D_SZ, H_SZ,
                b2 + (size_t)g * D_SZ, wbuf + g, G_SZ);
        } else {
            gemm_mfma<true, 2, true><<<dim3(D_SZ / 128, B_SZ / 128), 256, 0, stream>>>(
                asplit, Wt, out, D_SZ, B_SZ, D_SZ, H_SZ,
                b2 + (size_t)g * D_SZ, wbuf + g, G_SZ);
        }
    }
    (void)in_sizes; (void)n_in; (void)out_size; (void)ws_size;
}

// Round 7
// 2077.985 us; speedup vs baseline: 2.7134x; 1.3876x over previous
//
#include <hip/hip_runtime.h>
#include <math.h>

// GenreAdaptiveLayer — split-bf16 MFMA, z-batched over genres.
//
// items 0..10: item0 = attention GEMM (x·Wax), items 1..10 = genre g GEMMs.
// Per chunk of GBI items (ws_size-adaptive):
//   tr1[z]: Wt1 <- (item==0 ? Wa1[:D] : W1[g])^T  split bf16
//   tr2[z]: Wt2 <- W2[g]^T                        split bf16
//   gemm<3>[z]: hs[z] = split_bf16( x·W[item] + bias )   (bias=0 for item0)
//   (chunk0) scores_softmax: w[b,g] from hs[0] + aep
//   ln[z]:   hs[z] <- split_bf16( w * leaky(LN(hs[z])) )   in place
//   gemm<0>[z]: pbuf[z] = a[z]·W2[g]               fp32
//   reduce:  out (+)= sum_z pbuf[z] + sum_g w[b,g]*b2[g]
//
// K' = 3K split remap: hi*hi + lo*hi + hi*lo (lo*lo dropped, ~2^-18 rel).

#define B_SZ 4096
#define D_SZ 1024
#define H_SZ 2048
#define G_SZ 10
#define EPS_F 1e-5f
#define SLOPE_F 0.2f

#define SLOT_H_S  ((size_t)B_SZ * 2 * H_SZ)   // shorts per h slot (32 MB)
#define SLOT_WT_S ((size_t)4194304)           // shorts per Wt slot (8 MB)
#define SLOT_PB_F ((size_t)B_SZ * D_SZ)       // floats per partial (16 MB)

typedef __attribute__((ext_vector_type(8))) short short8;
typedef __attribute__((ext_vector_type(4))) float f32x4;

__device__ __forceinline__ unsigned short f2bf_rne(float f) {
    unsigned u = __float_as_uint(f);
    unsigned r = u + 0x7fffu + ((u >> 16) & 1u);
    return (unsigned short)(r >> 16);
}
__device__ __forceinline__ float bf2f(unsigned short u) {
    return __uint_as_float(((unsigned)u) << 16);
}

// ---------------------------------------------------------- x -> [hi|lo]
__global__ __launch_bounds__(256) void convert_x_split(
    const float* __restrict__ x, short* __restrict__ xs)
{
    const int idx = (blockIdx.x * 256 + threadIdx.x) * 8;
    const int b = idx >> 10;
    const int d = idx & (D_SZ - 1);
    float4 v0 = *reinterpret_cast<const float4*>(&x[idx]);
    float4 v1 = *reinterpret_cast<const float4*>(&x[idx + 4]);
    float v[8] = {v0.x, v0.y, v0.z, v0.w, v1.x, v1.y, v1.z, v1.w};
    short8 hi8, lo8;
#pragma unroll
    for (int e = 0; e < 8; e++) {
        unsigned short hb = f2bf_rne(v[e]);
        hi8[e] = (short)hb;
        lo8[e] = (short)f2bf_rne(v[e] - bf2f(hb));
    }
    *reinterpret_cast<short8*>(&xs[(size_t)b * (2 * D_SZ) + d]) = hi8;
    *reinterpret_cast<short8*>(&xs[(size_t)b * (2 * D_SZ) + D_SZ + d]) = lo8;
}

// ---------------- batched W (K,N) fp32 -> Wt[z] (N, 2K) bf16 [hi|lo]
// KIND 1: K=1024,N=2048, src = item==0 ? Wa1 : W1+(item-1)*K*N
// KIND 2: K=2048,N=1024, src = W2 + (i0+z)*K*N
template<int KIND>
__global__ __launch_bounds__(256) void transpose_split_b(
    const float* __restrict__ Wa1, const float* __restrict__ Wg,
    short* __restrict__ dstBase, int i0)
{
    const int K = (KIND == 1) ? D_SZ : H_SZ;
    const int N = (KIND == 1) ? H_SZ : D_SZ;
    const int z = blockIdx.z;
    const float* src;
    if (KIND == 1) {
        const int item = i0 + z;
        src = (item == 0) ? Wa1 : Wg + (size_t)(item - 1) * K * N;
    } else {
        src = Wg + (size_t)(i0 + z) * K * N;
    }
    short* dst = dstBase + (size_t)z * SLOT_WT_S;

    __shared__ float tile[32][33];
    const int k0 = blockIdx.x * 32, n0 = blockIdx.y * 32;
    const int tj = threadIdx.x & 31, ti = threadIdx.x >> 5;
#pragma unroll
    for (int p = 0; p < 4; p++) {
        int i = ti + p * 8;
        tile[i][tj] = src[(size_t)(k0 + i) * N + n0 + tj];
    }
    __syncthreads();
#pragma unroll
    for (int p = 0; p < 4; p++) {
        int i = ti + p * 8;
        float v = tile[tj][i];             // = src[k0+tj][n0+i]
        int orow = n0 + i, ocol = k0 + tj;
        unsigned short hb = f2bf_rne(v);
        unsigned short lb = f2bf_rne(v - bf2f(hb));
        dst[(size_t)orow * (2 * K) + ocol] = (short)hb;
        dst[(size_t)orow * (2 * K) + K + ocol] = (short)lb;
    }
}

// ---------------------------------------------------------------- GEMM
// split-K' = 3K remap over [hi|lo] A (M,2K) and Wt[z] (N,2K); fp32 acc.
// MODE 3: N=2048; Cs[z] = split(acc + bias[col]);  bias = z-item's b1 (or 0)
// MODE 0: N=1024; Cf[z] = acc;  A advances per z (a-slot per genre)
template<int MODE>
__global__ __launch_bounds__(256) void gemm_mfma(
    const short* __restrict__ A, int lda,
    const short* __restrict__ WtBase,
    float* __restrict__ CfBase, short* __restrict__ CsBase,
    int K, const float* __restrict__ b1,
    const float* __restrict__ zerob, int i0)
{
    __shared__ short As[128 * 32];
    __shared__ short Bs[128 * 32];
    const int tid = threadIdx.x;
    const int lane = tid & 63;
    const int w = tid >> 6;
    const int wm = w >> 1, wn = w & 1;
    const int bm0 = blockIdx.y * 128, bn0 = blockIdx.x * 128;
    const int z = blockIdx.z;

    const short* Az = (MODE == 0) ? A + (size_t)z * SLOT_H_S : A;
    const short* Bt = WtBase + (size_t)z * SLOT_WT_S;

    f32x4 acc[4][4];
#pragma unroll
    for (int i = 0; i < 4; i++)
#pragma unroll
        for (int j = 0; j < 4; j++) acc[i][j] = (f32x4)0.f;

    const int ksteps = 3 * K / 32;
    for (int t = 0; t < ksteps; t++) {
        const int kp = t * 32;
        const int aoff = kp < 2 * K ? kp : kp - 2 * K;
        const int boff = kp < K ? kp : kp - K;

        __syncthreads();  // previous iteration's frag reads complete
#pragma unroll
        for (int p = 0; p < 2; p++) {
            const int q = tid + p * 256;
            const int r = q >> 2, s = q & 3;
            const int lc = s ^ ((r >> 1) & 3);  // pre-swizzled source chunk
            const short* ga = Az + (size_t)(bm0 + r) * lda + aoff + lc * 8;
            const short* gb = Bt + (size_t)(bn0 + r) * lda + boff + lc * 8;
            __builtin_amdgcn_global_load_lds(
                (const __attribute__((address_space(1))) void*)ga,
                (__attribute__((address_space(3))) void*)(As + q * 8), 16, 0, 0);
            __builtin_amdgcn_global_load_lds(
                (const __attribute__((address_space(1))) void*)gb,
                (__attribute__((address_space(3))) void*)(Bs + q * 8), 16, 0, 0);
        }
        __syncthreads();

        const int fr = lane & 15, kc = lane >> 4;
        short8 af[4], bfr[4];
#pragma unroll
        for (int i = 0; i < 4; i++) {
            const int ar = wm * 64 + i * 16 + fr;
            af[i] = *reinterpret_cast<const short8*>(
                (const char*)As + ar * 64 + ((kc ^ ((ar >> 1) & 3)) << 4));
            const int br = wn * 64 + i * 16 + fr;
            bfr[i] = *reinterpret_cast<const short8*>(
                (const char*)Bs + br * 64 + ((kc ^ ((br >> 1) & 3)) << 4));
        }
#pragma unroll
        for (int i = 0; i < 4; i++)
#pragma unroll
            for (int j = 0; j < 4; j++)
                acc[i][j] = __builtin_amdgcn_mfma_f32_16x16x32_bf16(
                    af[i], bfr[j], acc[i][j], 0, 0, 0);
    }

    // epilogue: C/D layout col = lane&15, row = (lane>>4)*4 + reg
    const int fr = lane & 15, fq = lane >> 4;
    if (MODE == 0) {
        float* Cf = CfBase + (size_t)z * SLOT_PB_F;
#pragma unroll
        for (int i = 0; i < 4; i++)
#pragma unroll
            for (int j = 0; j < 4; j++) {
                const int col = bn0 + wn * 64 + j * 16 + fr;
                const int row0 = bm0 + wm * 64 + i * 16 + fq * 4;
#pragma unroll
                for (int r = 0; r < 4; r++)
                    Cf[(size_t)(row0 + r) * D_SZ + col] = acc[i][j][r];
            }
    } else {
        short* Cs = CsBase + (size_t)z * SLOT_H_S;
        const float* bias = (i0 + z == 0) ? zerob
                          : b1 + (size_t)(i0 + z - 1) * H_SZ;
#pragma unroll
        for (int i = 0; i < 4; i++)
#pragma unroll
            for (int j = 0; j < 4; j++) {
                const int col = bn0 + wn * 64 + j * 16 + fr;
                const float bv = bias[col];
                const int row0 = bm0 + wm * 64 + i * 16 + fq * 4;
#pragma unroll
                for (int r = 0; r < 4; r++) {
                    const float v = acc[i][j][r] + bv;
                    unsigned short hb = f2bf_rne(v);
                    unsigned short lb = f2bf_rne(v - bf2f(hb));
                    Cs[(size_t)(row0 + r) * (2 * H_SZ) + col] = (short)hb;
                    Cs[(size_t)(row0 + r) * (2 * H_SZ) + H_SZ + col] = (short)lb;
                }
            }
    }
}

// --------------------------------------------- aep[g,h] = ba1[h] (init)
__global__ __launch_bounds__(256) void aep_init(
    const float* __restrict__ ba1, float* __restrict__ aep)
{
    const int i = blockIdx.x * 256 + threadIdx.x;
    aep[i] = ba1[i & (H_SZ - 1)];
}

// -------------------------- aep[g,h] += sum_k emb[g,k]*Wa1[D+k][h]
__global__ __launch_bounds__(256) void ae_partial(
    const float* __restrict__ emb, const float* __restrict__ Wa1,
    float* __restrict__ aep)
{
    const int h = blockIdx.x * 256 + threadIdx.x;
    const int k0 = blockIdx.y * 256;
    float acc[G_SZ];
#pragma unroll
    for (int g = 0; g < G_SZ; g++) acc[g] = 0.f;
    for (int k = k0; k < k0 + 256; k++) {
        float wv = Wa1[(size_t)(D_SZ + k) * H_SZ + h];
#pragma unroll
        for (int g = 0; g < G_SZ; g++)
            acc[g] = fmaf(emb[g * H_SZ + k], wv, acc[g]);
    }
#pragma unroll
    for (int g = 0; g < G_SZ; g++) atomicAdd(&aep[(size_t)g * H_SZ + h], acc[g]);
}

// ------------- scores + softmax -> w[b,g]; ah read from split slot0
__global__ __launch_bounds__(64) void scores_softmax(
    const short* __restrict__ hs0, const float* __restrict__ aep,
    const float* __restrict__ Wa2, const float* __restrict__ ba2,
    float* __restrict__ w)
{
    const int b = blockIdx.x;
    const int lane = threadIdx.x;
    float accg[G_SZ];
#pragma unroll
    for (int g = 0; g < G_SZ; g++) accg[g] = 0.f;

    for (int j = 0; j < H_SZ / 64; j++) {
        const int h = j * 64 + lane;
        const float av = bf2f((unsigned short)hs0[(size_t)b * (2 * H_SZ) + h])
                       + bf2f((unsigned short)hs0[(size_t)b * (2 * H_SZ) + H_SZ + h]);
        const float wv = Wa2[h];
#pragma unroll
        for (int g = 0; g < G_SZ; g++) {
            float v = av + aep[(size_t)g * H_SZ + h];
            v = v > 0.f ? v : SLOPE_F * v;
            accg[g] = fmaf(v, wv, accg[g]);
        }
    }
#pragma unroll
    for (int g = 0; g < G_SZ; g++)
#pragma unroll
        for (int m = 1; m < 64; m <<= 1) accg[g] += __shfl_xor(accg[g], m, 64);

    if (lane == 0) {
        const float bb = ba2[0];
        float mx = -1e30f;
#pragma unroll
        for (int g = 0; g < G_SZ; g++) {
            accg[g] += bb;
            mx = fmaxf(mx, accg[g]);
        }
        float sum = 0.f;
#pragma unroll
        for (int g = 0; g < G_SZ; g++) {
            accg[g] = expf(accg[g] - mx);
            sum += accg[g];
        }
        const float inv = 1.f / sum;
#pragma unroll
        for (int g = 0; g < G_SZ; g++) w[(size_t)b * G_SZ + g] = accg[g] * inv;
    }
}

// ---- batched in-place: hs[zg] <- split( w * leaky(LN(hs[zg])) )
__global__ __launch_bounds__(256) void ln_split_b(
    short* __restrict__ hsBase,
    const float* __restrict__ ln_g, const float* __restrict__ ln_b,
    const float* __restrict__ wbuf, int g0)
{
    const int zg = blockIdx.y;
    const int g = g0 + zg;
    short* hs = hsBase + (size_t)zg * SLOT_H_S;
    const int b = blockIdx.x;
    const int tid = threadIdx.x;
    const int h0 = tid * 8;
    const int lane = tid & 63, wv_ = tid >> 6;
    __shared__ float red[8];

    short8 hi8 = *reinterpret_cast<const short8*>(&hs[(size_t)b * (2 * H_SZ) + h0]);
    short8 lo8 = *reinterpret_cast<const short8*>(&hs[(size_t)b * (2 * H_SZ) + H_SZ + h0]);
    float v[8];
#pragma unroll
    for (int e = 0; e < 8; e++)
        v[e] = bf2f((unsigned short)hi8[e]) + bf2f((unsigned short)lo8[e]);

    float s = 0.f, q = 0.f;
#pragma unroll
    for (int e = 0; e < 8; e++) { s += v[e]; q += v[e] * v[e]; }
#pragma unroll
    for (int m = 1; m < 64; m <<= 1) {
        s += __shfl_xor(s, m, 64);
        q += __shfl_xor(q, m, 64);
    }
    if (lane == 0) { red[wv_ * 2] = s; red[wv_ * 2 + 1] = q; }
    __syncthreads();
    float ts = red[0] + red[2] + red[4] + red[6];
    float tq = red[1] + red[3] + red[5] + red[7];
    const float mu = ts * (1.f / H_SZ);
    const float var = tq * (1.f / H_SZ) - mu * mu;
    const float rstd = rsqrtf(var + EPS_F);
    const float ww = wbuf[(size_t)b * G_SZ + g];

    const float* lngp = ln_g + (size_t)g * H_SZ;
    const float* lnbp = ln_b + (size_t)g * H_SZ;
    float4 g0v = *reinterpret_cast<const float4*>(&lngp[h0]);
    float4 g1v = *reinterpret_cast<const float4*>(&lngp[h0 + 4]);
    float4 e0v = *reinterpret_cast<const float4*>(&lnbp[h0]);
    float4 e1v = *reinterpret_cast<const float4*>(&lnbp[h0 + 4]);
    float gg[8] = {g0v.x, g0v.y, g0v.z, g0v.w, g1v.x, g1v.y, g1v.z, g1v.w};
    float bb[8] = {e0v.x, e0v.y, e0v.z, e0v.w, e1v.x, e1v.y, e1v.z, e1v.w};

    short8 ho8, lo8o;
#pragma unroll
    for (int e = 0; e < 8; e++) {
        float t = (v[e] - mu) * rstd * gg[e] + bb[e];
        t = t > 0.f ? t : SLOPE_F * t;
        float a = ww * t;
        unsigned short hb = f2bf_rne(a);
        ho8[e] = (short)hb;
        lo8o[e] = (short)f2bf_rne(a - bf2f(hb));
    }
    *reinterpret_cast<short8*>(&hs[(size_t)b * (2 * H_SZ) + h0]) = ho8;
    *reinterpret_cast<short8*>(&hs[(size_t)b * (2 * H_SZ) + H_SZ + h0]) = lo8o;
}

// ---- out (+)= sum_zg pbuf[zg] + sum w[b,g]*b2[g];  one block per row
template<bool FIRST>
__global__ __launch_bounds__(256) void reduce_out(
    const float* __restrict__ pbuf, int ng, int g0,
    const float* __restrict__ wbuf, const float* __restrict__ b2,
    float* __restrict__ out)
{
    const int b = blockIdx.x;
    const int c = threadIdx.x * 4;
    float4 acc;
    if (FIRST) acc = make_float4(0.f, 0.f, 0.f, 0.f);
    else acc = *reinterpret_cast<const float4*>(&out[(size_t)b * D_SZ + c]);
    for (int zg = 0; zg < ng; zg++) {
        float4 p = *reinterpret_cast<const float4*>(
            &pbuf[(size_t)zg * SLOT_PB_F + (size_t)b * D_SZ + c]);
        acc.x += p.x; acc.y += p.y; acc.z += p.z; acc.w += p.w;
    }
    for (int zg = 0; zg < ng; zg++) {
        const float wv = wbuf[(size_t)b * G_SZ + g0 + zg];
        float4 bv = *reinterpret_cast<const float4*>(&b2[(size_t)(g0 + zg) * D_SZ + c]);
        acc.x += wv * bv.x; acc.y += wv * bv.y;
        acc.z += wv * bv.z; acc.w += wv * bv.w;
    }
    *reinterpret_cast<float4*>(&out[(size_t)b * D_SZ + c]) = acc;
}

// ---------------------------------------------------------------- launch
extern "C" void kernel_launch(void* const* d_in, const int* in_sizes, int n_in,
                              void* d_out, int out_size, void* d_ws, size_t ws_size,
                              hipStream_t stream)
{
    const float* x    = (const float*)d_in[0];
    const float* emb  = (const float*)d_in[1];
    const float* W1   = (const float*)d_in[2];
    const float* b1   = (const float*)d_in[3];
    const float* ln_g = (const float*)d_in[4];
    const float* ln_b = (const float*)d_in[5];
    const float* W2   = (const float*)d_in[6];
    const float* b2   = (const float*)d_in[7];
    const float* Wa1  = (const float*)d_in[8];
    const float* ba1  = (const float*)d_in[9];
    const float* Wa2  = (const float*)d_in[10];
    const float* ba2  = (const float*)d_in[11];
    float* out = (float*)d_out;

    char* w8 = (char*)d_ws;
    short* x_split = (short*)w8;                       // 16,777,216 B
    float* aep     = (float*)(w8 + 16777216);          //     81,920 B
    float* wbuf    = (float*)(w8 + 16859136);          //    163,840 B
    float* zerob   = (float*)(w8 + 17022976);          //      8,192 B
    const size_t fixed = 17031168;
    size_t GBI = (ws_size > fixed + 67108864)
               ? (ws_size - fixed) / 67108864 : 1;
    if (GBI > 11) GBI = 11;
    if (GBI < 1) GBI = 1;
    short* wt1  = (short*)(w8 + fixed);
    short* wt2  = wt1 + GBI * SLOT_WT_S;
    short* hs   = wt2 + GBI * SLOT_WT_S;
    float* pbuf = (float*)(hs + GBI * SLOT_H_S);

    hipMemsetAsync(zerob, 0, 8192, stream);
    convert_x_split<<<(B_SZ * D_SZ / 8) / 256, 256, 0, stream>>>(x, x_split);
    aep_init<<<G_SZ * H_SZ / 256, 256, 0, stream>>>(ba1, aep);
    ae_partial<<<dim3(H_SZ / 256, 8), 256, 0, stream>>>(emb, Wa1, aep);

    int items_done = 0;
    while (items_done < 11) {
        const int i0 = items_done;
        const int ni = (11 - i0 < (int)GBI) ? (11 - i0) : (int)GBI;
        const int g0 = (i0 == 0) ? 0 : i0 - 1;      // first genre in chunk
        const int ng = (i0 == 0) ? ni - 1 : ni;     // genres in chunk
        const int gso = (i0 == 0) ? 1 : 0;          // genre slot offset

        transpose_split_b<1><<<dim3(32, 64, ni), 256, 0, stream>>>(
            Wa1, W1, wt1, i0);
        if (ng > 0)
            transpose_split_b<2><<<dim3(64, 32, ng), 256, 0, stream>>>(
                nullptr, W2, wt2, g0);

        gemm_mfma<3><<<dim3(16, 32, ni), 256, 0, stream>>>(
            x_split, 2 * D_SZ, wt1, nullptr, hs, D_SZ, b1, zerob, i0);

        if (i0 == 0)
            scores_softmax<<<B_SZ, 64, 0, stream>>>(hs, aep, Wa2, ba2, wbuf);

        if (ng > 0) {
            ln_split_b<<<dim3(B_SZ, ng), 256, 0, stream>>>(
                hs + (size_t)gso * SLOT_H_S, ln_g, ln_b, wbuf, g0);
            gemm_mfma<0><<<dim3(8, 32, ng), 256, 0, stream>>>(
                hs + (size_t)gso * SLOT_H_S, 2 * H_SZ, wt2, pbuf, nullptr,
                H_SZ, nullptr, nullptr, 0);
            if (g0 == 0)
                reduce_out<true><<<B_SZ, 256, 0, stream>>>(
                    pbuf, ng, g0, wbuf, b2, out);
            else
                reduce_out<false><<<B_SZ, 256, 0, stream>>>(
                    pbuf, ng, g0, wbuf, b2, out);
        }
        items_done += ni;
    }
    (void)in_sizes; (void)n_in; (void)out_size; (void)emb;
}